// Round 1
// baseline (382.253 us; speedup 1.0000x reference)
//
#include <hip/hip_runtime.h>

#define N 4096
#define D 512
#define BM 16
#define BN 128
#define NWAVES 8

typedef __attribute__((ext_vector_type(8))) short short8;
typedef __attribute__((ext_vector_type(4))) float f32x4;

// fp32 -> bf16 round-to-nearest-even (finite inputs)
__device__ __forceinline__ unsigned short f2bf(float f) {
    unsigned int u = __float_as_uint(f);
    u = (u + 0x7FFFu + ((u >> 16) & 1u)) >> 16;
    return (unsigned short)u;
}

// Cast Q fp32 -> bf16 row-major
__global__ void cast_kernel(const float* __restrict__ in, unsigned short* __restrict__ out) {
    int i = (blockIdx.x * 256 + threadIdx.x) * 4;
    float4 v = *(const float4*)(in + i);
    ushort4 o;
    o.x = f2bf(v.x); o.y = f2bf(v.y); o.z = f2bf(v.z); o.w = f2bf(v.w);
    *(ushort4*)(out + i) = o;
}

// K fp32 -> Kbf (bf16 row-major [N][D]) and Kt (bf16 transposed [D][N])
__global__ void transpose_kernel(const float* __restrict__ K,
                                 unsigned short* __restrict__ Kbf,
                                 unsigned short* __restrict__ Kt) {
    __shared__ unsigned short tile[32][33];
    const int tx = threadIdx.x;   // 0..31
    const int ty = threadIdx.y;   // 0..7
    const int d0 = blockIdx.x * 32;
    const int j0 = blockIdx.y * 32;
    #pragma unroll
    for (int i = 0; i < 4; ++i) {
        int j = j0 + ty + 8 * i;
        int d = d0 + tx;
        unsigned short b = f2bf(K[j * D + d]);
        Kbf[j * D + d] = b;
        tile[ty + 8 * i][tx] = b;
    }
    __syncthreads();
    #pragma unroll
    for (int i = 0; i < 4; ++i) {
        int d = d0 + ty + 8 * i;
        int j = j0 + tx;
        Kt[d * N + j] = tile[tx][ty + 8 * i];
    }
}

// Flash attention fwd, no-max-subtraction softmax (scores bounded by construction).
// Block: 512 threads = 8 waves, BM=16 query rows, BN=128 keys per tile.
// QK^T: wave wv owns key-cols [wv*16, wv*16+16); PV: wave wv owns d-cols [wv*64, wv*64+64).
__global__ __launch_bounds__(512) void flash_kernel(
    const unsigned short* __restrict__ Qbf,
    const unsigned short* __restrict__ Kbf,
    const unsigned short* __restrict__ Kt,
    const float* __restrict__ times,
    const float* __restrict__ w1,
    const float* __restrict__ b1,
    const float* __restrict__ w2,
    const float* __restrict__ b2,
    float* __restrict__ out)
{
    __shared__ unsigned short Pbuf[BM][BN + 8];   // +8 bf16 pad: breaks b128 bank aliasing
    __shared__ float lred[BM][NWAVES];

    const int tid  = threadIdx.x;
    const int wv   = tid >> 6;
    const int lane = tid & 63;
    const int q4   = lane >> 4;    // quad
    const int l16  = lane & 15;
    const int R0   = blockIdx.x * BM;

    // Q A-fragments, resident in registers: A[m=l16][k=q4*8+j] per 32-wide k-block
    short8 qfrag[16];
    {
        const unsigned short* qp = Qbf + (size_t)(R0 + l16) * D + q4 * 8;
        #pragma unroll
        for (int kb = 0; kb < 16; ++kb)
            qfrag[kb] = *(const short8*)(qp + kb * 32);
    }

    float tr[4];
    #pragma unroll
    for (int r = 0; r < 4; ++r) tr[r] = times[R0 + q4 * 4 + r];

    float w1v[8], b1v[8], w2v[8];
    #pragma unroll
    for (int k = 0; k < 8; ++k) { w1v[k] = w1[k]; b1v[k] = b1[k]; w2v[k] = w2[k]; }
    const float b2v = b2[0];

    const float scale = 0.04419417382415922f;  // 1/sqrt(512)

    f32x4 of[4] = { {0,0,0,0}, {0,0,0,0}, {0,0,0,0}, {0,0,0,0} };
    float lacc[4] = {0.f, 0.f, 0.f, 0.f};

    for (int kt = 0; kt < N / BN; ++kt) {
        const int j0 = kt * BN;

        // ---- S chunk = Q[16 x 512] . K[cols]^T : B-frags straight from global bf16 ----
        f32x4 c = {0, 0, 0, 0};
        const unsigned short* kp = Kbf + (size_t)(j0 + wv * 16 + l16) * D + q4 * 8;
        #pragma unroll
        for (int kb = 0; kb < 16; ++kb) {
            short8 bfrag = *(const short8*)(kp + kb * 32);
            c = __builtin_amdgcn_mfma_f32_16x16x32_bf16(qfrag[kb], bfrag, c, 0, 0, 0);
        }

        // ---- time-weight MLP + scale + exp (no max subtraction; |s| <= ~6) ----
        const float tc = times[j0 + wv * 16 + l16];
        float p[4];
        #pragma unroll
        for (int r = 0; r < 4; ++r) {
            float td = fabsf(tr[r] - tc);
            float acc = b2v;
            #pragma unroll
            for (int k = 0; k < 8; ++k)
                acc += w2v[k] * fmaxf(td * w1v[k] + b1v[k], 0.f);
            float twt = 1.0f / (1.0f + __expf(-acc));
            float s = c[r] * scale * twt;
            float e = __expf(s);
            p[r] = e;
            lacc[r] += e;
        }

        // ---- P to LDS (C-layout -> A-layout transform) ----
        #pragma unroll
        for (int r = 0; r < 4; ++r)
            Pbuf[q4 * 4 + r][wv * 16 + l16] = f2bf(p[r]);
        __syncthreads();

        // ---- O chunk += P[16 x 128] . V[128 x dcols], V^T frags from global bf16 ----
        #pragma unroll
        for (int ks = 0; ks < 4; ++ks) {
            short8 afrag = *(const short8*)(&Pbuf[l16][ks * 32 + q4 * 8]);
            #pragma unroll
            for (int dt = 0; dt < 4; ++dt) {
                const unsigned short* vp = Kt + (size_t)(wv * 64 + dt * 16 + l16) * N
                                              + j0 + ks * 32 + q4 * 8;
                short8 bfrag = *(const short8*)(vp);
                of[dt] = __builtin_amdgcn_mfma_f32_16x16x32_bf16(afrag, bfrag, of[dt], 0, 0, 0);
            }
        }
        __syncthreads();   // Pbuf reused next tile
    }

    // ---- denominator: butterfly over 16 lanes, then across 8 waves via LDS ----
    float lrow[4];
    #pragma unroll
    for (int r = 0; r < 4; ++r) {
        float v = lacc[r];
        v += __shfl_xor(v, 1);
        v += __shfl_xor(v, 2);
        v += __shfl_xor(v, 4);
        v += __shfl_xor(v, 8);
        lrow[r] = v;
    }
    if (l16 == 0) {
        #pragma unroll
        for (int r = 0; r < 4; ++r) lred[q4 * 4 + r][wv] = lrow[r];
    }
    __syncthreads();

    #pragma unroll
    for (int r = 0; r < 4; ++r) {
        float s = 0.f;
        #pragma unroll
        for (int w = 0; w < NWAVES; ++w) s += lred[q4 * 4 + r][w];
        const float inv = 1.0f / s;
        const int row = R0 + q4 * 4 + r;
        #pragma unroll
        for (int dt = 0; dt < 4; ++dt)
            out[(size_t)row * D + wv * 64 + dt * 16 + l16] = of[dt][r] * inv;
    }
}

extern "C" void kernel_launch(void* const* d_in, const int* in_sizes, int n_in,
                              void* d_out, int out_size, void* d_ws, size_t ws_size,
                              hipStream_t stream) {
    const float* q     = (const float*)d_in[0];
    const float* hist  = (const float*)d_in[1];
    const float* times = (const float*)d_in[2];
    const float* w1    = (const float*)d_in[3];
    const float* b1    = (const float*)d_in[4];
    const float* w2    = (const float*)d_in[5];
    const float* b2    = (const float*)d_in[6];
    float* out = (float*)d_out;

    unsigned short* Qbf = (unsigned short*)d_ws;          // 4 MB
    unsigned short* Kbf = Qbf + (size_t)N * D;            // 4 MB
    unsigned short* Kt  = Kbf + (size_t)N * D;            // 4 MB (transposed)

    cast_kernel<<<(N * D) / (256 * 4), 256, 0, stream>>>(q, Qbf);
    transpose_kernel<<<dim3(D / 32, N / 32), dim3(32, 8), 0, stream>>>(hist, Kbf, Kt);
    flash_kernel<<<N / BM, 512, 0, stream>>>(Qbf, Kbf, Kt, times, w1, b1, w2, b2, out);
}

// Round 2
// 353.356 us; speedup vs baseline: 1.0818x; 1.0818x over previous
//
#include <hip/hip_runtime.h>

#define N 4096
#define D 512
#define BM 16
#define BN 128
#define KS 4              // key-split factor
#define CHUNK (N / KS)    // 1024 keys per block
#define NWAVES 8

typedef __attribute__((ext_vector_type(8))) short short8;
typedef __attribute__((ext_vector_type(4))) float f32x4;

// fp32 -> bf16 round-to-nearest-even (finite inputs)
__device__ __forceinline__ unsigned short f2bf(float f) {
    unsigned int u = __float_as_uint(f);
    u = (u + 0x7FFFu + ((u >> 16) & 1u)) >> 16;
    return (unsigned short)u;
}

// Cast Q fp32 -> bf16 row-major
__global__ void cast_kernel(const float* __restrict__ in, unsigned short* __restrict__ out) {
    int i = (blockIdx.x * 256 + threadIdx.x) * 4;
    float4 v = *(const float4*)(in + i);
    ushort4 o;
    o.x = f2bf(v.x); o.y = f2bf(v.y); o.z = f2bf(v.z); o.w = f2bf(v.w);
    *(ushort4*)(out + i) = o;
}

// K fp32 -> Kbf (bf16 row-major [N][D]) and Kt (bf16 transposed [D][N])
__global__ void transpose_kernel(const float* __restrict__ K,
                                 unsigned short* __restrict__ Kbf,
                                 unsigned short* __restrict__ Kt) {
    __shared__ unsigned short tile[32][33];
    const int tx = threadIdx.x;   // 0..31
    const int ty = threadIdx.y;   // 0..7
    const int d0 = blockIdx.x * 32;
    const int j0 = blockIdx.y * 32;
    #pragma unroll
    for (int i = 0; i < 4; ++i) {
        int j = j0 + ty + 8 * i;
        int d = d0 + tx;
        unsigned short b = f2bf(K[j * D + d]);
        Kbf[j * D + d] = b;
        tile[ty + 8 * i][tx] = b;
    }
    __syncthreads();
    #pragma unroll
    for (int i = 0; i < 4; ++i) {
        int d = d0 + ty + 8 * i;
        int j = j0 + tx;
        Kt[d * N + j] = tile[tx][ty + 8 * i];
    }
}

// Flash-attention partial over one key chunk. No-max-subtraction softmax
// (scores bounded: |s| <= ~6 by construction), so exp-sum and numerator are
// linear in the key chunks -> accumulate partials with device atomics.
// Block: 512 threads = 8 waves, BM=16 query rows, BN=128 keys per tile,
// CHUNK/BN = 8 tiles per block.
__global__ __launch_bounds__(512) void flash_partial_kernel(
    const unsigned short* __restrict__ Qbf,
    const unsigned short* __restrict__ Kbf,
    const unsigned short* __restrict__ Kt,
    const float* __restrict__ times,
    const float* __restrict__ w1,
    const float* __restrict__ b1,
    const float* __restrict__ w2,
    const float* __restrict__ b2,
    float* __restrict__ out,      // numerator accumulator (pre-zeroed)
    float* __restrict__ denom)    // [N] exp-sum accumulator (pre-zeroed)
{
    __shared__ unsigned short Pbuf[BM][BN + 8];   // +8 bf16 pad: breaks b128 bank aliasing
    __shared__ float lred[BM][NWAVES];

    const int tid  = threadIdx.x;
    const int wv   = tid >> 6;
    const int lane = tid & 63;
    const int q4   = lane >> 4;    // quad
    const int l16  = lane & 15;
    const int R0   = blockIdx.x * BM;
    const int C0   = blockIdx.y * CHUNK;

    // Q A-fragments, resident in registers: A[m=l16][k=q4*8+j] per 32-wide k-block
    short8 qfrag[16];
    {
        const unsigned short* qp = Qbf + (size_t)(R0 + l16) * D + q4 * 8;
        #pragma unroll
        for (int kb = 0; kb < 16; ++kb)
            qfrag[kb] = *(const short8*)(qp + kb * 32);
    }

    float tr[4];
    #pragma unroll
    for (int r = 0; r < 4; ++r) tr[r] = times[R0 + q4 * 4 + r];

    float w1v[8], b1v[8], w2v[8];
    #pragma unroll
    for (int k = 0; k < 8; ++k) { w1v[k] = w1[k]; b1v[k] = b1[k]; w2v[k] = w2[k]; }
    const float b2v = b2[0];

    const float scale = 0.04419417382415922f;  // 1/sqrt(512)

    f32x4 of[4] = { {0,0,0,0}, {0,0,0,0}, {0,0,0,0}, {0,0,0,0} };
    float lacc[4] = {0.f, 0.f, 0.f, 0.f};

    for (int kt = 0; kt < CHUNK / BN; ++kt) {
        const int j0 = C0 + kt * BN;

        // ---- S chunk = Q[16 x 512] . K[cols]^T : B-frags straight from global bf16 ----
        f32x4 c = {0, 0, 0, 0};
        const unsigned short* kp = Kbf + (size_t)(j0 + wv * 16 + l16) * D + q4 * 8;
        #pragma unroll
        for (int kb = 0; kb < 16; ++kb) {
            short8 bfrag = *(const short8*)(kp + kb * 32);
            c = __builtin_amdgcn_mfma_f32_16x16x32_bf16(qfrag[kb], bfrag, c, 0, 0, 0);
        }

        // ---- time-weight MLP + scale + exp (no max subtraction; |s| <= ~6) ----
        const float tc = times[j0 + wv * 16 + l16];
        float p[4];
        #pragma unroll
        for (int r = 0; r < 4; ++r) {
            float td = fabsf(tr[r] - tc);
            float acc = b2v;
            #pragma unroll
            for (int k = 0; k < 8; ++k)
                acc += w2v[k] * fmaxf(td * w1v[k] + b1v[k], 0.f);
            float twt = 1.0f / (1.0f + __expf(-acc));
            float s = c[r] * scale * twt;
            float e = __expf(s);
            p[r] = e;
            lacc[r] += e;
        }

        // ---- P to LDS (C-layout -> A-layout transform) ----
        #pragma unroll
        for (int r = 0; r < 4; ++r)
            Pbuf[q4 * 4 + r][wv * 16 + l16] = f2bf(p[r]);
        __syncthreads();

        // ---- O chunk += P[16 x 128] . V[128 x dcols], V^T frags from global bf16 ----
        #pragma unroll
        for (int ks = 0; ks < 4; ++ks) {
            short8 afrag = *(const short8*)(&Pbuf[l16][ks * 32 + q4 * 8]);
            #pragma unroll
            for (int dt = 0; dt < 4; ++dt) {
                const unsigned short* vp = Kt + (size_t)(wv * 64 + dt * 16 + l16) * N
                                              + j0 + ks * 32 + q4 * 8;
                short8 bfrag = *(const short8*)(vp);
                of[dt] = __builtin_amdgcn_mfma_f32_16x16x32_bf16(afrag, bfrag, of[dt], 0, 0, 0);
            }
        }
        __syncthreads();   // Pbuf reused next tile
    }

    // ---- partial denominator: butterfly over 16 cols, cross-wave via LDS, one atomic/row ----
    float lrow[4];
    #pragma unroll
    for (int r = 0; r < 4; ++r) {
        float v = lacc[r];
        v += __shfl_xor(v, 1);
        v += __shfl_xor(v, 2);
        v += __shfl_xor(v, 4);
        v += __shfl_xor(v, 8);
        lrow[r] = v;
    }
    if (l16 == 0) {
        #pragma unroll
        for (int r = 0; r < 4; ++r) lred[q4 * 4 + r][wv] = lrow[r];
    }
    __syncthreads();
    if (wv == 0 && lane < BM) {
        float s = 0.f;
        #pragma unroll
        for (int w = 0; w < NWAVES; ++w) s += lred[lane][w];
        atomicAdd(denom + R0 + lane, s);
    }

    // ---- partial numerator: coalesced fp32 atomics into out ----
    #pragma unroll
    for (int r = 0; r < 4; ++r) {
        const int row = R0 + q4 * 4 + r;
        #pragma unroll
        for (int dt = 0; dt < 4; ++dt)
            atomicAdd(out + (size_t)row * D + wv * 64 + dt * 16 + l16, of[dt][r]);
    }
}

// out[i, :] /= denom[i]   (one float4 per thread)
__global__ void normalize_kernel(float* __restrict__ out, const float* __restrict__ denom) {
    int i = blockIdx.x * 256 + threadIdx.x;   // float4 index
    int row = i >> 7;                          // (i*4) / 512
    float inv = 1.0f / denom[row];
    float4 v = ((const float4*)out)[i];
    v.x *= inv; v.y *= inv; v.z *= inv; v.w *= inv;
    ((float4*)out)[i] = v;
}

extern "C" void kernel_launch(void* const* d_in, const int* in_sizes, int n_in,
                              void* d_out, int out_size, void* d_ws, size_t ws_size,
                              hipStream_t stream) {
    const float* q     = (const float*)d_in[0];
    const float* hist  = (const float*)d_in[1];
    const float* times = (const float*)d_in[2];
    const float* w1    = (const float*)d_in[3];
    const float* b1    = (const float*)d_in[4];
    const float* w2    = (const float*)d_in[5];
    const float* b2    = (const float*)d_in[6];
    float* out = (float*)d_out;

    unsigned short* Qbf = (unsigned short*)d_ws;          // 4 MB
    unsigned short* Kbf = Qbf + (size_t)N * D;            // 4 MB
    unsigned short* Kt  = Kbf + (size_t)N * D;            // 4 MB (transposed)
    float* denom = (float*)(Kt + (size_t)N * D);          // 16 KB

    hipMemsetAsync(out, 0, (size_t)N * D * sizeof(float), stream);
    hipMemsetAsync(denom, 0, (size_t)N * sizeof(float), stream);

    cast_kernel<<<(N * D) / (256 * 4), 256, 0, stream>>>(q, Qbf);
    transpose_kernel<<<dim3(D / 32, N / 32), dim3(32, 8), 0, stream>>>(hist, Kbf, Kt);
    flash_partial_kernel<<<dim3(N / BM, KS), 512, 0, stream>>>(
        Qbf, Kbf, Kt, times, w1, b1, w2, b2, out, denom);
    normalize_kernel<<<(N * D / 4) / 256, 256, 0, stream>>>(out, denom);
}

// Round 3
// 222.563 us; speedup vs baseline: 1.7175x; 1.5877x over previous
//
#include <hip/hip_runtime.h>

#define N 4096
#define D 512
#define BM 64
#define BN 64
#define KS 4
#define CHUNK (N / KS)        // 1024 keys per block
#define NTILES (CHUNK / BN)   // 16 tiles

typedef __attribute__((ext_vector_type(4))) short short4v;
typedef __attribute__((ext_vector_type(8))) short short8;
typedef __attribute__((ext_vector_type(4))) float f32x4;

// fp32 -> bf16 round-to-nearest-even (finite inputs)
__device__ __forceinline__ unsigned short f2bf(float f) {
    unsigned int u = __float_as_uint(f);
    u = (u + 0x7FFFu + ((u >> 16) & 1u)) >> 16;
    return (unsigned short)u;
}

// async global -> LDS, 16B per lane (global addr per-lane, LDS dst = base + lane*16)
__device__ __forceinline__ void load_lds16(const void* g, void* l) {
    __builtin_amdgcn_global_load_lds(
        (const __attribute__((address_space(1))) void*)g,
        (__attribute__((address_space(3))) void*)l, 16, 0, 0);
}

// Cast Q fp32 -> bf16 row-major
__global__ void cast_kernel(const float* __restrict__ in, unsigned short* __restrict__ out) {
    int i = (blockIdx.x * 256 + threadIdx.x) * 4;
    float4 v = *(const float4*)(in + i);
    ushort4 o;
    o.x = f2bf(v.x); o.y = f2bf(v.y); o.z = f2bf(v.z); o.w = f2bf(v.w);
    *(ushort4*)(out + i) = o;
}

// K fp32 -> Kbf (bf16 row-major [N][D]) and Kt (bf16 transposed [D][N])
__global__ void transpose_kernel(const float* __restrict__ K,
                                 unsigned short* __restrict__ Kbf,
                                 unsigned short* __restrict__ Kt) {
    __shared__ unsigned short tile[32][33];
    const int tx = threadIdx.x;   // 0..31
    const int ty = threadIdx.y;   // 0..7
    const int d0 = blockIdx.x * 32;
    const int j0 = blockIdx.y * 32;
    #pragma unroll
    for (int i = 0; i < 4; ++i) {
        int j = j0 + ty + 8 * i;
        int d = d0 + tx;
        unsigned short b = f2bf(K[j * D + d]);
        Kbf[j * D + d] = b;
        tile[ty + 8 * i][tx] = b;
    }
    __syncthreads();
    #pragma unroll
    for (int i = 0; i < 4; ++i) {
        int d = d0 + ty + 8 * i;
        int j = j0 + tx;
        Kt[d * N + j] = tile[tx][ty + 8 * i];
    }
}

// Flash-attention partial, BM=64 Q-rows x CHUNK=1024 keys per block.
// 8 waves: wr = wv&1 (32-row strip), wc = wv>>1 (16-key col strip for QK^T,
// 128-dcol strip for PV). K/Kt tiles staged in LDS in MFMA-fragment-linear
// order via global_load_lds (all frag reads = conflict-free lane*16B b128).
__global__ __launch_bounds__(512, 2) void flash_partial_kernel(
    const unsigned short* __restrict__ Qbf,
    const unsigned short* __restrict__ Kbf,
    const unsigned short* __restrict__ Kt,
    const float* __restrict__ times,
    const float* __restrict__ w1,
    const float* __restrict__ b1,
    const float* __restrict__ w2,
    const float* __restrict__ b2,
    float* __restrict__ out,      // numerator accumulator (pre-zeroed)
    float* __restrict__ denom)    // [N] exp-sum accumulator (pre-zeroed)
{
    extern __shared__ unsigned short smem[];
    unsigned short* Ks  = smem;                  // 64 frags x 512 elems = 64 KB
    unsigned short* Kts = smem + 32768;          // 64 frags x 512 elems = 64 KB
    unsigned short* Pb  = smem + 65536;          // [64][68] bf16 = 8.5 KB
    float* lred = (float*)(smem + 65536 + 4352); // [64][4]

    const int tid  = threadIdx.x;
    const int wv   = tid >> 6;
    const int lane = tid & 63;
    const int q4   = lane >> 4;
    const int l16  = lane & 15;
    const int wr   = wv & 1;       // row strip (32 rows)
    const int wc   = wv >> 1;      // 0..3
    const int R0   = blockIdx.x * BM;
    const int C0   = blockIdx.y * CHUNK;

    // Q A-fragments resident in regs: rows wr*32 + r2*16 + l16, d = kb*32 + q4*8
    short8 qfrag[2][16];
    #pragma unroll
    for (int r2 = 0; r2 < 2; ++r2) {
        const unsigned short* qp = Qbf + (size_t)(R0 + wr * 32 + r2 * 16 + l16) * D + q4 * 8;
        #pragma unroll
        for (int kb = 0; kb < 16; ++kb)
            qfrag[r2][kb] = *(const short8*)(qp + kb * 32);
    }

    float tr[2][4];
    #pragma unroll
    for (int r2 = 0; r2 < 2; ++r2)
        #pragma unroll
        for (int ri = 0; ri < 4; ++ri)
            tr[r2][ri] = times[R0 + wr * 32 + r2 * 16 + q4 * 4 + ri];

    float w1v[8], b1v[8], w2v[8];
    #pragma unroll
    for (int k = 0; k < 8; ++k) { w1v[k] = w1[k]; b1v[k] = b1[k]; w2v[k] = w2[k]; }
    const float b2v = b2[0];
    const float scale = 0.04419417382415922f;  // 1/sqrt(512)

    f32x4 of[2][8];
    #pragma unroll
    for (int r2 = 0; r2 < 2; ++r2)
        #pragma unroll
        for (int dt = 0; dt < 8; ++dt) of[r2][dt] = (f32x4){0.f, 0.f, 0.f, 0.f};
    float lacc[2][4] = {{0.f,0.f,0.f,0.f},{0.f,0.f,0.f,0.f}};

    for (int kt = 0; kt < NTILES; ++kt) {
        const int j0 = C0 + kt * BN;

        __syncthreads();   // previous tile's LDS reads complete before overwrite

        // ---- stage K tile: frag f = kb*4 + wcf, slot = f*512 + lane*8 ----
        #pragma unroll
        for (int i = 0; i < 8; ++i) {
            int f = wv * 8 + i;
            int kb = f >> 2, wcf = f & 3;
            const unsigned short* g = Kbf + (size_t)(j0 + wcf * 16 + l16) * D + kb * 32 + q4 * 8;
            load_lds16(g, Ks + f * 512 + lane * 8);
        }
        // ---- stage Kt tile: frag f = ks*32 + wd*8 + dt ----
        #pragma unroll
        for (int i = 0; i < 8; ++i) {
            int f = wv * 8 + i;
            int ks = f >> 5, wd = (f >> 3) & 3, dt = f & 7;
            const unsigned short* g = Kt + (size_t)(wd * 128 + dt * 16 + l16) * N
                                         + j0 + ks * 32 + q4 * 8;
            load_lds16(g, Kts + f * 512 + lane * 8);
        }
        __syncthreads();   // staging visible (drains vmcnt)

        // ---- QK^T: S strip [32 rows x 16 keys], B-frags conflict-free from Ks ----
        f32x4 c[2] = { {0,0,0,0}, {0,0,0,0} };
        #pragma unroll
        for (int kb = 0; kb < 16; ++kb) {
            short8 b = *(const short8*)(Ks + (kb * 4 + wc) * 512 + lane * 8);
            c[0] = __builtin_amdgcn_mfma_f32_16x16x32_bf16(qfrag[0][kb], b, c[0], 0, 0, 0);
            c[1] = __builtin_amdgcn_mfma_f32_16x16x32_bf16(qfrag[1][kb], b, c[1], 0, 0, 0);
        }

        // ---- time-weight MLP + scale + exp; write P (C-layout -> padded LDS) ----
        const float tc = times[j0 + wc * 16 + l16];
        #pragma unroll
        for (int r2 = 0; r2 < 2; ++r2) {
            #pragma unroll
            for (int ri = 0; ri < 4; ++ri) {
                float td = fabsf(tr[r2][ri] - tc);
                float acc = b2v;
                #pragma unroll
                for (int k = 0; k < 8; ++k)
                    acc += w2v[k] * fmaxf(td * w1v[k] + b1v[k], 0.f);
                float twt = 1.0f / (1.0f + __expf(-acc));
                float s = c[r2][ri] * scale * twt;
                float e = __expf(s);
                lacc[r2][ri] += e;
                Pb[(wr * 32 + r2 * 16 + q4 * 4 + ri) * 68 + wc * 16 + l16] = f2bf(e);
            }
        }
        __syncthreads();   // P visible

        // ---- PV: O[32 rows x 128 dcols] += P . V ----
        #pragma unroll
        for (int ks = 0; ks < 2; ++ks) {
            short8 a[2];
            #pragma unroll
            for (int r2 = 0; r2 < 2; ++r2) {
                const unsigned short* pp = Pb + ((wr * 2 + r2) * 16 + l16) * 68 + ks * 32 + q4 * 8;
                short4v lo = *(const short4v*)pp;
                short4v hi = *(const short4v*)(pp + 4);
                a[r2] = __builtin_shufflevector(lo, hi, 0, 1, 2, 3, 4, 5, 6, 7);
            }
            #pragma unroll
            for (int dt = 0; dt < 8; ++dt) {
                short8 b = *(const short8*)(Kts + (ks * 32 + wc * 8 + dt) * 512 + lane * 8);
                of[0][dt] = __builtin_amdgcn_mfma_f32_16x16x32_bf16(a[0], b, of[0][dt], 0, 0, 0);
                of[1][dt] = __builtin_amdgcn_mfma_f32_16x16x32_bf16(a[1], b, of[1][dt], 0, 0, 0);
            }
        }
    }

    // ---- partial denominator: butterfly over 16 cols, cross-wave via lred ----
    float lrow[2][4];
    #pragma unroll
    for (int r2 = 0; r2 < 2; ++r2) {
        #pragma unroll
        for (int ri = 0; ri < 4; ++ri) {
            float v = lacc[r2][ri];
            v += __shfl_xor(v, 1);
            v += __shfl_xor(v, 2);
            v += __shfl_xor(v, 4);
            v += __shfl_xor(v, 8);
            lrow[r2][ri] = v;
        }
    }
    if (l16 == 0) {
        #pragma unroll
        for (int r2 = 0; r2 < 2; ++r2)
            #pragma unroll
            for (int ri = 0; ri < 4; ++ri)
                lred[(wr * 32 + r2 * 16 + q4 * 4 + ri) * 4 + wc] = lrow[r2][ri];
    }
    __syncthreads();
    if (tid < BM) {
        float s = lred[tid * 4 + 0] + lred[tid * 4 + 1] + lred[tid * 4 + 2] + lred[tid * 4 + 3];
        atomicAdd(denom + R0 + tid, s);
    }

    // ---- partial numerator: coalesced fp32 atomics ----
    #pragma unroll
    for (int r2 = 0; r2 < 2; ++r2) {
        #pragma unroll
        for (int ri = 0; ri < 4; ++ri) {
            const int row = R0 + wr * 32 + r2 * 16 + q4 * 4 + ri;
            #pragma unroll
            for (int dt = 0; dt < 8; ++dt)
                atomicAdd(out + (size_t)row * D + wc * 128 + dt * 16 + l16, of[r2][dt][ri]);
        }
    }
}

// out[i, :] /= denom[i]   (one float4 per thread)
__global__ void normalize_kernel(float* __restrict__ out, const float* __restrict__ denom) {
    int i = blockIdx.x * 256 + threadIdx.x;   // float4 index
    int row = i >> 7;
    float inv = 1.0f / denom[row];
    float4 v = ((const float4*)out)[i];
    v.x *= inv; v.y *= inv; v.z *= inv; v.w *= inv;
    ((float4*)out)[i] = v;
}

extern "C" void kernel_launch(void* const* d_in, const int* in_sizes, int n_in,
                              void* d_out, int out_size, void* d_ws, size_t ws_size,
                              hipStream_t stream) {
    const float* q     = (const float*)d_in[0];
    const float* hist  = (const float*)d_in[1];
    const float* times = (const float*)d_in[2];
    const float* w1    = (const float*)d_in[3];
    const float* b1    = (const float*)d_in[4];
    const float* w2    = (const float*)d_in[5];
    const float* b2    = (const float*)d_in[6];
    float* out = (float*)d_out;

    unsigned short* Qbf = (unsigned short*)d_ws;          // 4 MB
    unsigned short* Kbf = Qbf + (size_t)N * D;            // 4 MB
    unsigned short* Kt  = Kbf + (size_t)N * D;            // 4 MB (transposed)
    float* denom = (float*)(Kt + (size_t)N * D);          // 16 KB

    // LDS: 64KB Ks + 64KB Kts + 8.5KB P + 1KB lred
    const size_t lds_bytes = (size_t)(32768 + 32768 + 4352) * 2 + 64 * 4 * 4;
    hipFuncSetAttribute((const void*)flash_partial_kernel,
                        hipFuncAttributeMaxDynamicSharedMemorySize, 160 * 1024);

    hipMemsetAsync(out, 0, (size_t)N * D * sizeof(float), stream);
    hipMemsetAsync(denom, 0, (size_t)N * sizeof(float), stream);

    cast_kernel<<<(N * D) / (256 * 4), 256, 0, stream>>>(q, Qbf);
    transpose_kernel<<<dim3(D / 32, N / 32), dim3(32, 8), 0, stream>>>(hist, Kbf, Kt);
    flash_partial_kernel<<<dim3(N / BM, KS), 512, lds_bytes, stream>>>(
        Qbf, Kbf, Kt, times, w1, b1, w2, b2, out, denom);
    normalize_kernel<<<(N * D / 4) / 256, 256, 0, stream>>>(out, denom);
}

// Round 4
// 217.879 us; speedup vs baseline: 1.7544x; 1.0215x over previous
//
#include <hip/hip_runtime.h>

#define N 4096
#define D 512
#define BM 64
#define BN 64
#define KS 4
#define CHUNK (N / KS)          // 1024 keys per block
#define NTILES (CHUNK / BN)     // 16 tiles per block
#define NKT (N / BN)            // 64 key tiles total
#define FRAG_SH 512             // shorts per 16x32 fragment (1 KB)
#define TILE_SH (64 * FRAG_SH)  // shorts per key tile (64 frags = 64 KB)
#define PB_W 72                 // Pb row stride (shorts): 16B-aligned, bank-shift 4/row

typedef __attribute__((ext_vector_type(8))) short short8;
typedef __attribute__((ext_vector_type(4))) float f32x4;

// fp32 -> bf16 round-to-nearest-even (finite inputs)
__device__ __forceinline__ unsigned short f2bf(float f) {
    unsigned int u = __float_as_uint(f);
    u = (u + 0x7FFFu + ((u >> 16) & 1u)) >> 16;
    return (unsigned short)u;
}
// fast fp32 -> bf16, round-to-nearest (ties away) — 2 VALU ops
__device__ __forceinline__ unsigned short f2bf_rn(float f) {
    return (unsigned short)((__float_as_uint(f) + 0x8000u) >> 16);
}

// async global -> LDS, 16B/lane; LDS dst must be uniform base + lane*16
__device__ __forceinline__ void load_lds16(const unsigned short* g, unsigned short* l) {
    __builtin_amdgcn_global_load_lds(
        (const __attribute__((address_space(1))) void*)g,
        (__attribute__((address_space(3))) void*)l, 16, 0, 0);
}

// Q fp32 -> bf16, pre-scaled by 1/sqrt(D)
__global__ void prep_q(const float* __restrict__ in, unsigned short* __restrict__ out) {
    int i = (blockIdx.x * 256 + threadIdx.x) * 4;
    const float s = 0.04419417382415922f;
    float4 v = *(const float4*)(in + i);
    ushort4 o;
    o.x = f2bf(v.x * s); o.y = f2bf(v.y * s); o.z = f2bf(v.z * s); o.w = f2bf(v.w * s);
    *(ushort4*)(out + i) = o;
}

// K fp32 -> fragment-linear blocked layouts.
// Kblk[t][f=kb*4+wc][lane*8+j]: B[n=key wc*16+l16][k=d kb*32+q4*8+j]   (QK^T B-frags)
// Vblk[t][g=ks*32+nb][lane*8+j]: B[n=dcol nb*16+l16][k=key ks*32+q4*8+j] (PV B-frags)
// One block per (tile t, half h): rows h*32..h*32+31 of the 64-key tile.
__global__ __launch_bounds__(256) void prep_kv(const float* __restrict__ K,
                                               unsigned short* __restrict__ Kblk,
                                               unsigned short* __restrict__ Vblk) {
    __shared__ unsigned short tile[32 * 512];   // 32 KB
    const int t = blockIdx.x >> 1;
    const int h = blockIdx.x & 1;
    const int tid = threadIdx.x;

    #pragma unroll
    for (int k = 0; k < 16; ++k) {
        int idx = tid + k * 256;           // float4 slot, 4096 total
        int row = idx >> 7;                // 0..31 (local)
        int c4  = (idx & 127) << 2;
        float4 v = *(const float4*)(K + (size_t)(t * 64 + h * 32 + row) * D + c4);
        ushort4 o;
        o.x = f2bf(v.x); o.y = f2bf(v.y); o.z = f2bf(v.z); o.w = f2bf(v.w);
        *(ushort4*)(tile + row * 512 + c4) = o;
    }
    __syncthreads();

    // Kblk frags with wc in {2h, 2h+1}
    #pragma unroll
    for (int k = 0; k < 8; ++k) {
        int s = tid + k * 256;             // short8 slot, 2048 total
        int fl = s >> 6, lane = s & 63;
        int kb = fl >> 1, wcl = fl & 1, wc = 2 * h + wcl;
        int l16 = lane & 15, q4 = lane >> 4;
        short8 v = *(const short8*)(tile + (wcl * 16 + l16) * 512 + kb * 32 + q4 * 8);
        *(short8*)(Kblk + (size_t)t * TILE_SH + ((size_t)(kb * 4 + wc)) * FRAG_SH + lane * 8) = v;
    }
    // Vblk frags with ks == h
    #pragma unroll
    for (int k = 0; k < 8; ++k) {
        int s = tid + k * 256;
        int nb = s >> 6, lane = s & 63;
        int g = h * 32 + nb;
        int l16 = lane & 15, q4 = lane >> 4;
        unsigned short tmp[8];
        #pragma unroll
        for (int j = 0; j < 8; ++j)
            tmp[j] = tile[(q4 * 8 + j) * 512 + nb * 16 + l16];
        *(short8*)(Vblk + (size_t)t * TILE_SH + (size_t)g * FRAG_SH + lane * 8) = *(const short8*)tmp;
    }
}

// Flash-attention partial. 8 waves: wr=wv&1 (32-row strip), wc=wv>>1 (0..3).
// K tiles double-buffered in LDS (contiguous 1KB global_load_lds per frag);
// V B-frags read directly from blocked global Vblk (coalesced dwordx4, L2-hot);
// Q A-frags register-resident. Prefetch of tile kt+1 issued after the P-barrier
// so it hides under the PV phase and no barrier drains it early.
__global__ __launch_bounds__(512, 2) void flash_kernel(
    const unsigned short* __restrict__ Qbf,
    const unsigned short* __restrict__ Kblk,
    const unsigned short* __restrict__ Vblk,
    const float* __restrict__ times,
    const float* __restrict__ w1,
    const float* __restrict__ b1,
    const float* __restrict__ w2,
    const float* __restrict__ b2,
    float* __restrict__ out,      // numerator accumulator (pre-zeroed)
    float* __restrict__ denom)    // [N] exp-sum accumulator (pre-zeroed)
{
    extern __shared__ unsigned short smem[];
    unsigned short* Ks0 = smem;                       // 64 KB
    unsigned short* Ks1 = smem + TILE_SH;             // 64 KB
    unsigned short* Pb  = smem + 2 * TILE_SH;         // 64 x 72 shorts = 9 KB
    float* lred = (float*)(smem + 2 * TILE_SH + 64 * PB_W);  // [64][4]

    const int tid  = threadIdx.x;
    const int wv   = tid >> 6;
    const int lane = tid & 63;
    const int q4   = lane >> 4;
    const int l16  = lane & 15;
    const int wr   = wv & 1;
    const int wc   = wv >> 1;     // 0..3
    const int bx   = blockIdx.x;
    const int chunk = bx & 3;     // XCD-affine under round-robin dispatch (perf heuristic)
    const int R0   = (bx >> 2) * BM;
    const int T0   = chunk * NTILES;

    // Q A-frags (pre-scaled by 1/sqrt(D)): rows wr*32 + r2*16 + l16
    short8 qfrag[2][16];
    #pragma unroll
    for (int r2 = 0; r2 < 2; ++r2) {
        const unsigned short* qp = Qbf + (size_t)(R0 + wr * 32 + r2 * 16 + l16) * D + q4 * 8;
        #pragma unroll
        for (int kb = 0; kb < 16; ++kb)
            qfrag[r2][kb] = *(const short8*)(qp + kb * 32);
    }

    float tr[2][4];
    #pragma unroll
    for (int r2 = 0; r2 < 2; ++r2)
        #pragma unroll
        for (int ri = 0; ri < 4; ++ri)
            tr[r2][ri] = times[R0 + wr * 32 + r2 * 16 + q4 * 4 + ri];

    float w1v[8], b1v[8], w2v[8];
    #pragma unroll
    for (int k = 0; k < 8; ++k) { w1v[k] = w1[k]; b1v[k] = b1[k]; w2v[k] = w2[k]; }
    const float b2v = b2[0];
    // b1 == 0 (and td >= 0) collapses the MLP: sum_k w2k*relu(td*w1k) = td * C1
    bool fast = true;
    #pragma unroll
    for (int k = 0; k < 8; ++k) fast = fast && (b1v[k] == 0.0f);
    float C1 = 0.0f;
    #pragma unroll
    for (int k = 0; k < 8; ++k) C1 += w2v[k] * fmaxf(w1v[k], 0.0f);

    f32x4 of[2][8];
    #pragma unroll
    for (int r2 = 0; r2 < 2; ++r2)
        #pragma unroll
        for (int dt = 0; dt < 8; ++dt) of[r2][dt] = (f32x4){0.f, 0.f, 0.f, 0.f};
    float lacc[2][4] = {{0.f,0.f,0.f,0.f},{0.f,0.f,0.f,0.f}};

    // preload tile 0 into Ks0
    {
        const unsigned short* src = Kblk + (size_t)T0 * TILE_SH;
        #pragma unroll
        for (int i = 0; i < 8; ++i) {
            int f = wv * 8 + i;
            load_lds16(src + (size_t)f * FRAG_SH + lane * 8, Ks0 + f * FRAG_SH + lane * 8);
        }
    }

    for (int kt = 0; kt < NTILES; ++kt) {
        unsigned short* KsCur = (kt & 1) ? Ks1 : Ks0;
        unsigned short* KsNxt = (kt & 1) ? Ks0 : Ks1;
        const int tglob = T0 + kt;

        __syncthreads();   // KsCur staged (had full prior PV phase to land); Pb free

        // ---- QK^T: per wave 32 rows x 16 keys, B-frags conflict-free from LDS ----
        f32x4 c[2] = { {0,0,0,0}, {0,0,0,0} };
        #pragma unroll
        for (int kb = 0; kb < 16; ++kb) {
            short8 b = *(const short8*)(KsCur + (kb * 4 + wc) * FRAG_SH + lane * 8);
            c[0] = __builtin_amdgcn_mfma_f32_16x16x32_bf16(qfrag[0][kb], b, c[0], 0, 0, 0);
            c[1] = __builtin_amdgcn_mfma_f32_16x16x32_bf16(qfrag[1][kb], b, c[1], 0, 0, 0);
        }

        // ---- time-weight (collapsed MLP) + exp; P -> LDS (C-layout -> A-layout) ----
        const float tc = times[tglob * BN + wc * 16 + l16];
        #pragma unroll
        for (int r2 = 0; r2 < 2; ++r2) {
            #pragma unroll
            for (int ri = 0; ri < 4; ++ri) {
                float td = fabsf(tr[r2][ri] - tc);
                float a = fmaf(td, C1, b2v);
                if (!fast) {
                    a = b2v;
                    #pragma unroll
                    for (int k = 0; k < 8; ++k)
                        a += w2v[k] * fmaxf(fmaf(td, w1v[k], b1v[k]), 0.f);
                }
                float twt = __builtin_amdgcn_rcpf(1.0f + __expf(-a));
                float s = c[r2][ri] * twt;      // 1/sqrt(D) pre-folded into Q
                float e = __expf(s);
                lacc[r2][ri] += e;
                Pb[(wr * 32 + r2 * 16 + q4 * 4 + ri) * PB_W + wc * 16 + l16] = f2bf_rn(e);
            }
        }
        __syncthreads();   // P visible

        // ---- prefetch next K tile (after barrier: hides under PV, never drained early) ----
        if (kt + 1 < NTILES) {
            const unsigned short* src = Kblk + (size_t)(tglob + 1) * TILE_SH;
            #pragma unroll
            for (int i = 0; i < 8; ++i) {
                int f = wv * 8 + i;
                load_lds16(src + (size_t)f * FRAG_SH + lane * 8, KsNxt + f * FRAG_SH + lane * 8);
            }
        }

        // ---- PV: per wave 32 rows x 128 dcols; B-frags coalesced from global Vblk ----
        const unsigned short* Vt = Vblk + (size_t)tglob * TILE_SH;
        #pragma unroll
        for (int ks = 0; ks < 2; ++ks) {
            short8 a2[2];
            #pragma unroll
            for (int r2 = 0; r2 < 2; ++r2)
                a2[r2] = *(const short8*)(Pb + ((wr * 2 + r2) * 16 + l16) * PB_W + ks * 32 + q4 * 8);
            #pragma unroll
            for (int dt = 0; dt < 8; ++dt) {
                short8 b = *(const short8*)(Vt + (ks * 32 + wc * 8 + dt) * FRAG_SH + lane * 8);
                of[0][dt] = __builtin_amdgcn_mfma_f32_16x16x32_bf16(a2[0], b, of[0][dt], 0, 0, 0);
                of[1][dt] = __builtin_amdgcn_mfma_f32_16x16x32_bf16(a2[1], b, of[1][dt], 0, 0, 0);
            }
        }
    }

    // ---- partial denominator: butterfly over 16 cols, cross-wave via lred ----
    float lrow[2][4];
    #pragma unroll
    for (int r2 = 0; r2 < 2; ++r2) {
        #pragma unroll
        for (int ri = 0; ri < 4; ++ri) {
            float v = lacc[r2][ri];
            v += __shfl_xor(v, 1);
            v += __shfl_xor(v, 2);
            v += __shfl_xor(v, 4);
            v += __shfl_xor(v, 8);
            lrow[r2][ri] = v;
        }
    }
    if (l16 == 0) {
        #pragma unroll
        for (int r2 = 0; r2 < 2; ++r2)
            #pragma unroll
            for (int ri = 0; ri < 4; ++ri)
                lred[(wr * 32 + r2 * 16 + q4 * 4 + ri) * 4 + wc] = lrow[r2][ri];
    }
    __syncthreads();
    if (tid < BM) {
        float s = lred[tid * 4 + 0] + lred[tid * 4 + 1] + lred[tid * 4 + 2] + lred[tid * 4 + 3];
        atomicAdd(denom + R0 + tid, s);
    }

    // ---- partial numerator: coalesced fp32 atomics ----
    #pragma unroll
    for (int r2 = 0; r2 < 2; ++r2) {
        #pragma unroll
        for (int ri = 0; ri < 4; ++ri) {
            const int row = R0 + wr * 32 + r2 * 16 + q4 * 4 + ri;
            #pragma unroll
            for (int dt = 0; dt < 8; ++dt)
                atomicAdd(out + (size_t)row * D + wc * 128 + dt * 16 + l16, of[r2][dt][ri]);
        }
    }
}

// out[i, :] /= denom[i]
__global__ void normalize_kernel(float* __restrict__ out, const float* __restrict__ denom) {
    int i = blockIdx.x * 256 + threadIdx.x;   // float4 index
    int row = i >> 7;
    float inv = 1.0f / denom[row];
    float4 v = ((const float4*)out)[i];
    v.x *= inv; v.y *= inv; v.z *= inv; v.w *= inv;
    ((float4*)out)[i] = v;
}

extern "C" void kernel_launch(void* const* d_in, const int* in_sizes, int n_in,
                              void* d_out, int out_size, void* d_ws, size_t ws_size,
                              hipStream_t stream) {
    const float* q     = (const float*)d_in[0];
    const float* hist  = (const float*)d_in[1];
    const float* times = (const float*)d_in[2];
    const float* w1    = (const float*)d_in[3];
    const float* b1    = (const float*)d_in[4];
    const float* w2    = (const float*)d_in[5];
    const float* b2    = (const float*)d_in[6];
    float* out = (float*)d_out;

    unsigned short* Qbf  = (unsigned short*)d_ws;         // 4 MB
    unsigned short* Kblk = Qbf + (size_t)N * D;           // 4 MB (fragment-linear)
    unsigned short* Vblk = Kblk + (size_t)N * D;          // 4 MB (fragment-linear)
    float* denom = (float*)(Vblk + (size_t)N * D);        // 16 KB

    // LDS: 2x64KB K double-buffer + Pb + lred
    const size_t lds_bytes = (size_t)2 * TILE_SH * 2 + 64 * PB_W * 2 + 64 * 4 * 4;
    hipFuncSetAttribute((const void*)flash_kernel,
                        hipFuncAttributeMaxDynamicSharedMemorySize, 160 * 1024);

    hipMemsetAsync(out, 0, (size_t)N * D * sizeof(float), stream);
    hipMemsetAsync(denom, 0, (size_t)N * sizeof(float), stream);

    prep_q<<<(N * D) / (256 * 4), 256, 0, stream>>>(q, Qbf);
    prep_kv<<<NKT * 2, 256, 0, stream>>>(hist, Kblk, Vblk);
    flash_kernel<<<N / BM * KS, 512, lds_bytes, stream>>>(
        Qbf, Kblk, Vblk, times, w1, b1, w2, b2, out, denom);
    normalize_kernel<<<(N * D / 4) / 256, 256, 0, stream>>>(out, denom);
}